// Round 9
// baseline (262.846 us; speedup 1.0000x reference)
//
#include <hip/hip_runtime.h>
#include <hip/hip_bf16.h>
#include <stdint.h>

typedef __attribute__((ext_vector_type(8))) short bf16x8;
typedef __attribute__((ext_vector_type(4))) float f32x4;
typedef __attribute__((address_space(1))) const void g_void;
typedef __attribute__((address_space(3))) void l_void;

#define NB 16
#define NC 256
#define NHW 4096
#define NT 72      // K-steps: 9 taps x 8 ci-blocks
#define TSLOT 8192 // one operand tile: 128 rows x 32 k x 2B

// ---------- prep: x NCHW f32 -> xt2 [b][cib][4096 pix][32 ci] bf16 (+zp init) ----
__global__ __launch_bounds__(256) void prep_xt2(const float* __restrict__ x,
                                                __hip_bfloat16* __restrict__ xt2,
                                                float* __restrict__ zp) {
  __shared__ float tile[64][65];
  const int b = blockIdx.z;
  const int cb = blockIdx.y << 6;
  const int pb = blockIdx.x << 6;
  if (blockIdx.x == 0 && blockIdx.y == 0 && blockIdx.z == 0) {
#pragma unroll
    for (int q = 0; q < 8; ++q) zp[(q << 8) + threadIdx.x] = 0.f;
  }
  const float* xs = x + ((size_t)(b * NC + cb) << 12) + pb;
#pragma unroll
  for (int k = 0; k < 16; ++k) {
    int idx = threadIdx.x + (k << 8);
    int c = idx >> 6, p = idx & 63;
    tile[p][c] = xs[((size_t)c << 12) + p];
  }
  __syncthreads();
#pragma unroll
  for (int k = 0; k < 16; ++k) {
    int idx = threadIdx.x + (k << 8);
    int p = idx >> 6, c = idx & 63;
    int P = pb + p, C = cb + c;
    xt2[((size_t)(b * 8 + (C >> 5)) << 17) + ((size_t)P << 5) + (C & 31)] =
        __float2bfloat16(tile[p][c]);
  }
}

// ---------- prep: kernel [b][co][ci][3][3] f32 -> kt2 [b][ct][tn][128][32] bf16 ----
// tn = cib*9+s; chunk pre-swizzled: stored-slot = chunk ^ ((row>>1)&3)
__global__ __launch_bounds__(256) void prep_kt2(const float* __restrict__ kin,
                                                __hip_bfloat16* __restrict__ kt2) {
  const int bco = blockIdx.x;  // b*256 + co
  const int b = bco >> 8, co = bco & 255;
  const size_t base = (size_t)bco * 2304;
  const int ci = threadIdx.x;
  float v[9];
#pragma unroll
  for (int s = 0; s < 9; ++s) v[s] = kin[base + ci * 9 + s];
  const int cib = ci >> 5, chunk = (ci >> 3) & 3, e = ci & 7;
  const int row = co & 127, ct = co >> 7;
  const int sc = chunk ^ ((row >> 1) & 3);
#pragma unroll
  for (int s = 0; s < 9; ++s) {
    const size_t dst = (((size_t)(b * 2 + ct) * NT + (cib * 9 + s)) << 12) +
                       (row << 5) + (sc << 3) + e;
    kt2[dst] = __float2bfloat16(v[s]);
  }
}

// ---------- implicit-GEMM conv, 128x128 tile, 4 blocks/CU exact fill ----
// A: 2-slot (16KB) 1-step lead; K: 3-slot (24KB) 2-step lead; total 40KB LDS.
// PASS 1: A=image(M=pixel), B=kernel(N=co), out = ht2 bf16 [b][cib][pix][32] (relu)
// PASS 2: A=kernel(M=co), B=image(N=pixel), out = fp32 NCHW (x + .., relu)
template <int PASS>
__global__ __launch_bounds__(256, 4) void conv_gemm(
    const __hip_bfloat16* __restrict__ img2,  // [B][8][4096][32] (xt2 or ht2)
    const __hip_bfloat16* __restrict__ kt2,   // [B][2][72][128][32] pre-swizzled
    const float* __restrict__ xres,           // pass2 residual (NCHW f32)
    const __hip_bfloat16* __restrict__ zp,    // 8KB zeros
    void* __restrict__ outp) {
  __shared__ __align__(16) char L[5 * TSLOT];  // A slots 0..1 | K slots 2..4

  const int tid = threadIdx.x;
  const int lane = tid & 63;
  const int wid = tid >> 6;  // 0..3
  const int wm = wid >> 1, wn = wid & 1;

  // XCD-affine: XCD x owns logical 128-block chunk = 2 complete samples
  const int orig = blockIdx.x;
  const int g = ((orig & 7) << 7) + (orig >> 3);
  const int b = g >> 6;
  const int t = g & 63;
  const int ptile = t >> 1;
  const int ct = t & 1;
  const int pbase = ptile << 7;

  const char* xb = (const char*)img2 + ((size_t)b << 21);  // sample base (bytes)
  const char* ktb = (const char*)kt2 + (((size_t)(b * 2 + ct) * NT) << 13);
  const char* zpb = (const char*)zp;

  // staging lane geometry: instr covers 16 rows; lane -> row +(lane>>2),
  // HW LDS slot lane&3; source chunk pre-swizzled: sch = (lane&3) ^ ((srow>>1)&3)
  const int srow = lane >> 2;
  const int sch = (lane & 3) ^ ((srow >> 1) & 3);

  // fragment read offsets (bytes)
  const int wI = (PASS == 1) ? wm : wn;  // image-side wave coord
  const int wK = (PASS == 1) ? wn : wm;  // kernel-side wave coord
  int ioff[4], koff[4];
#pragma unroll
  for (int f = 0; f < 4; ++f) {
    const int ir = (wI << 6) + (f << 4) + (lane & 15);
    ioff[f] = (ir << 6) + ((((lane >> 4) ^ ((ir >> 1) & 3))) << 4);
    const int kr = (wK << 6) + (f << 4) + (lane & 15);
    koff[f] = (kr << 6) + ((((lane >> 4) ^ ((kr >> 1) & 3))) << 4);
  }
  const bool killlo = (lane & 15) == 0;
  const bool killhi = (lane & 15) == 15;
  const bf16x8 z8 = {0, 0, 0, 0, 0, 0, 0, 0};

  f32x4 acc[4][4];
#pragma unroll
  for (int i = 0; i < 4; ++i)
#pragma unroll
    for (int j = 0; j < 4; ++j) acc[i][j] = (f32x4){0.f, 0.f, 0.f, 0.f};

  // A-tile stage: one contiguous 8KB block at tap offset (dh*64+dw)*64B.
  // h-OOB groups -> zp; w-edge wrap killed at fragment read.
  auto stageA = [&](int slot, int cibp, int dh, int dw, bool dummy) {
    const char* cb = xb + ((size_t)(cibp & 7) << 18);
#pragma unroll
    for (int i = 0; i < 2; ++i) {
      const int grp = (i << 2) + wid;
      const int h = (ptile << 1) + (grp >> 2) + dh;  // uniform per instr
      const bool ok = !dummy && ((unsigned)h < 64u);
      const int off = ((pbase + (grp << 4) + srow + (dh << 6) + dw) << 6) + (sch << 4);
      const char* src = ok ? cb + off : zpb + (lane << 4);
      __builtin_amdgcn_global_load_lds((g_void*)src,
                                       (l_void*)(L + slot * TSLOT + (grp << 10)), 16, 0, 0);
    }
  };
  auto stageK = [&](int slot, int tn) {
    const char* src0 = ktb + ((size_t)tn << 13);
#pragma unroll
    for (int i = 0; i < 2; ++i) {
      const int grp = (i << 2) + wid;
      const char* src = (tn < NT) ? src0 + (grp << 10) + (lane << 4) : zpb + (lane << 4);
      __builtin_amdgcn_global_load_lds(
          (g_void*)src, (l_void*)(L + (2 + slot) * TSLOT + (grp << 10)), 16, 0, 0);
    }
  };

  // prologue (issue order matters for vmcnt): K(0), A(0), K(1)  -> 6 ops in flight
  stageK(0, 0);
  stageA(0, 0, -1, -1, false);
  stageK(1, 1);

#pragma unroll 1
  for (int t18 = 0; t18 < 4; ++t18) {
    const int base = t18 * 18;
#pragma unroll
    for (int u = 0; u < 18; ++u) {  // u: A-parity u&1, K-slot u%3, tap u%9 compile-time
      const int kk = base + u;
      const int s = u % 9;
      // steady state in-flight (oldest first): K(kk)x2, A(kk)x2, K(kk+1)x2.
      // vmcnt(2) drains K(kk)+A(kk); K(kk+1) rides through the barrier.
      asm volatile("s_waitcnt vmcnt(2)" ::: "memory");
      __builtin_amdgcn_s_barrier();
      {
        const int s1 = (u + 1) % 9;            // compile-time tap of step kk+1
        const int cib1 = (kk + 1) / 9;         // uniform runtime
        stageA((u + 1) & 1, cib1, s1 / 3 - 1, s1 % 3 - 1, kk + 1 >= NT);
        stageK((u + 2) % 3, kk + 2);
      }

      const char* As = L + (u & 1) * TSLOT;
      const char* Ks = L + (2 + u % 3) * TSLOT;
      bf16x8 fi[4], fk[4];
#pragma unroll
      for (int f = 0; f < 4; ++f) fi[f] = *(const bf16x8*)(As + ioff[f]);
#pragma unroll
      for (int f = 0; f < 4; ++f) fk[f] = *(const bf16x8*)(Ks + koff[f]);
      // w-edge wrap masking (compile-time tap)
      const int dw = s % 3 - 1;
      if (dw == 1) fi[3] = killhi ? z8 : fi[3];
      if (dw == -1) fi[0] = killlo ? z8 : fi[0];

#pragma unroll
      for (int i = 0; i < 4; ++i)
#pragma unroll
        for (int j = 0; j < 4; ++j) {
          if (PASS == 1)
            acc[i][j] = __builtin_amdgcn_mfma_f32_16x16x32_bf16(fi[i], fk[j], acc[i][j], 0, 0, 0);
          else
            acc[i][j] = __builtin_amdgcn_mfma_f32_16x16x32_bf16(fk[i], fi[j], acc[i][j], 0, 0, 0);
        }
    }
  }
  // drain tail dummy LDS-DMA before epilogue/endpgm
  asm volatile("s_waitcnt vmcnt(0)" ::: "memory");
  __builtin_amdgcn_sched_barrier(0);

  const int lg = lane >> 4;
  const int ln = lane & 15;
  if (PASS == 1) {
    __hip_bfloat16* ho = (__hip_bfloat16*)outp;  // ht2 layout [b][cib][pix][32]
#pragma unroll
    for (int i = 0; i < 4; ++i)
#pragma unroll
      for (int j = 0; j < 4; ++j)
#pragma unroll
        for (int r = 0; r < 4; ++r) {
          int pixel = pbase + (wm << 6) + (i << 4) + (lg << 2) + r;
          int co = (ct << 7) + (wn << 6) + (j << 4) + ln;
          float v = acc[i][j][r];
          v = v > 0.f ? v : 0.f;
          ho[((size_t)(b * 8 + (co >> 5)) << 17) + ((size_t)pixel << 5) + (co & 31)] =
              __float2bfloat16(v);
        }
  } else {
    float* oo = (float*)outp;
#pragma unroll
    for (int i = 0; i < 4; ++i)
#pragma unroll
      for (int j = 0; j < 4; ++j)
#pragma unroll
        for (int r = 0; r < 4; ++r) {
          int co = (ct << 7) + (wm << 6) + (i << 4) + (lg << 2) + r;
          int pixel = pbase + (wn << 6) + (j << 4) + ln;
          size_t idx = ((size_t)(b * NC + co) << 12) + pixel;
          float v = acc[i][j][r] + xres[idx];
          oo[idx] = v > 0.f ? v : 0.f;
        }
  }
}

extern "C" void kernel_launch(void* const* d_in, const int* in_sizes, int n_in,
                              void* d_out, int out_size, void* d_ws, size_t ws_size,
                              hipStream_t stream) {
  const float* x = (const float*)d_in[0];
  const float* k1 = (const float*)d_in[1];
  const float* k2 = (const float*)d_in[2];

  // ws: pad 256B | xt2 (33.6MB) | ht2 (33.6MB) | kt2 (18.9MB) | zp (8KB)
  // (pad so the pixel=-1 speculative read before xt2 stays in mapped memory)
  char* w = (char*)d_ws;
  __hip_bfloat16* xt2 = (__hip_bfloat16*)(w + 256);
  __hip_bfloat16* ht2 = xt2 + (size_t)NB * 8 * NHW * 32;
  __hip_bfloat16* kt2 = ht2 + (size_t)NB * 8 * NHW * 32;
  float* zp = (float*)(kt2 + (size_t)NB * 2 * NT * 128 * 32);

  prep_xt2<<<dim3(64, 4, NB), 256, 0, stream>>>(x, xt2, zp);
  prep_kt2<<<dim3(NB * NC), 256, 0, stream>>>(k1, kt2);
  conv_gemm<1><<<dim3(1024), 256, 0, stream>>>(xt2, kt2, nullptr,
                                               (const __hip_bfloat16*)zp, (void*)ht2);
  prep_kt2<<<dim3(NB * NC), 256, 0, stream>>>(k2, kt2);
  conv_gemm<2><<<dim3(1024), 256, 0, stream>>>(ht2, kt2, x,
                                               (const __hip_bfloat16*)zp, d_out);
}

// Round 10
// 185.969 us; speedup vs baseline: 1.4134x; 1.4134x over previous
//
#include <hip/hip_runtime.h>
#include <hip/hip_bf16.h>
#include <stdint.h>

typedef __attribute__((ext_vector_type(8))) short bf16x8;
typedef __attribute__((ext_vector_type(4))) float f32x4;
typedef __attribute__((address_space(1))) const void g_void;
typedef __attribute__((address_space(3))) void l_void;

#define NB 16
#define NC 256
#define NHW 4096
#define NT 72        // K-steps: 9 taps x 8 ci-blocks
#define SLOTB 32768  // per pipeline slot: IMG 16KB + KER 16KB

// ---------- prep: x NCHW f32 -> xt2 [b][cib][4096 pix][32 ci] bf16 (+zp init) ----
__global__ __launch_bounds__(256) void prep_xt2(const float* __restrict__ x,
                                                __hip_bfloat16* __restrict__ xt2,
                                                float* __restrict__ zp) {
  __shared__ float tile[64][65];
  const int b = blockIdx.z;
  const int cb = blockIdx.y << 6;
  const int pb = blockIdx.x << 6;
  if (blockIdx.x == 0 && blockIdx.y == 0 && blockIdx.z == 0) {
#pragma unroll
    for (int q = 0; q < 8; ++q) zp[(q << 8) + threadIdx.x] = 0.f;
  }
  const float* xs = x + ((size_t)(b * NC + cb) << 12) + pb;
#pragma unroll
  for (int k = 0; k < 16; ++k) {
    int idx = threadIdx.x + (k << 8);
    int c = idx >> 6, p = idx & 63;
    tile[p][c] = xs[((size_t)c << 12) + p];
  }
  __syncthreads();
#pragma unroll
  for (int k = 0; k < 16; ++k) {
    int idx = threadIdx.x + (k << 8);
    int p = idx >> 6, c = idx & 63;
    int P = pb + p, C = cb + c;
    xt2[((size_t)(b * 8 + (C >> 5)) << 17) + ((size_t)P << 5) + (C & 31)] =
        __float2bfloat16(tile[p][c]);
  }
}

// ---------- prep: kernel [b][co][ci][3][3] f32 -> kt2 [b][tn][256 co][32 k] bf16 ----
// tn = cib*9+s; 16KB contiguous per (b,tn); chunk pre-swizzled:
// stored-slot = chunk ^ ((co>>1)&3)
__global__ __launch_bounds__(256) void prep_kt2(const float* __restrict__ kin,
                                                __hip_bfloat16* __restrict__ kt2) {
  const int bco = blockIdx.x;  // b*256 + co
  const int b = bco >> 8, co = bco & 255;
  const size_t base = (size_t)bco * 2304;
  const int ci = threadIdx.x;
  float v[9];
#pragma unroll
  for (int s = 0; s < 9; ++s) v[s] = kin[base + ci * 9 + s];
  const int cib = ci >> 5, chunk = (ci >> 3) & 3, e = ci & 7;
  const int sc = chunk ^ ((co >> 1) & 3);
#pragma unroll
  for (int s = 0; s < 9; ++s) {
    const size_t dst = (((size_t)(b * NT + cib * 9 + s)) << 13) +
                       (co << 5) + (sc << 3) + e;
    kt2[dst] = __float2bfloat16(v[s]);
  }
}

// ---------- implicit-GEMM conv, 256x256 tile, 8-phase, contiguous staging ----
// PASS 1: A=image(M=pixel), B=kernel(N=co), out = ht2 bf16 [b][cib][pix][32] (relu)
// PASS 2: A=kernel(M=co), B=image(N=pixel), out = fp32 NCHW (x + .., relu)
template <int PASS>
__global__ __launch_bounds__(512, 2) void conv_gemm(
    const __hip_bfloat16* __restrict__ img2,  // [B][8][4096][32] (xt2 or ht2)
    const __hip_bfloat16* __restrict__ kt2,   // [B][72][256][32] pre-swizzled
    const float* __restrict__ xres,           // pass2 residual (NCHW f32)
    const __hip_bfloat16* __restrict__ zp,    // 8KB zeros
    void* __restrict__ outp) {
  __shared__ __align__(16) char L[4 * SLOTB];  // slot: [IMG 16KB | KER 16KB]

  const int tid = threadIdx.x;
  const int lane = tid & 63;
  const int wid = tid >> 6;  // 0..7
  const int wm = wid >> 2;   // 0..1  (M half: 128 rows)
  const int wn = wid & 3;    // 0..3  (N quarter: 64 cols)

  // XCD-affine: XCD x owns 32 logical blocks = 2 complete samples
  const int orig = blockIdx.x;
  const int g = ((orig & 7) << 5) + (orig >> 3);
  const int b = g >> 4;
  const int ptile = g & 15;
  const int pbase = ptile << 8;  // 256 pixels

  const char* xb = (const char*)img2 + ((size_t)b << 21);         // 2MB/sample
  const char* ktb = (const char*)kt2 + ((size_t)(b * NT) << 14);  // 16KB/tn
  const char* zpb = (const char*)zp;

  // staging lane geometry: each instr = 16 rows x 64B contiguous; lane -> row
  // +(lane>>2), HW slot lane&3; pre-swizzled source chunk
  const int srow = lane >> 2;
  const int sch = (lane & 3) ^ ((srow >> 1) & 3);

  // fragment read offsets (bytes): A rows = wm*128 + i*16, B rows = wn*64 + j*16
  int aoff[8], boff[4];
#pragma unroll
  for (int i = 0; i < 8; ++i) {
    const int ma = (wm << 7) + (i << 4) + (lane & 15);
    aoff[i] = (ma << 6) + ((((lane >> 4) ^ ((ma >> 1) & 3))) << 4);
  }
#pragma unroll
  for (int j = 0; j < 4; ++j) {
    const int nb = (wn << 6) + (j << 4) + (lane & 15);
    boff[j] = (nb << 6) + ((((lane >> 4) ^ ((nb >> 1) & 3))) << 4);
  }
  const bool killlo = (lane & 15) == 0;
  const bool killhi = (lane & 15) == 15;
  const bf16x8 z8 = {0, 0, 0, 0, 0, 0, 0, 0};

  f32x4 acc[8][4];
#pragma unroll
  for (int i = 0; i < 8; ++i)
#pragma unroll
    for (int j = 0; j < 4; ++j) acc[i][j] = (f32x4){0.f, 0.f, 0.f, 0.f};

  // image tile stage: 16KB contiguous at tap offset; per-instr uniform h-redirect
  auto stageI = [&](int tn, int cibp, int dh, int dw, bool dummy) {
    char* dst0 = L + (tn & 3) * SLOTB;  // IMG at +0
    const char* cb = xb + ((size_t)(cibp & 7) << 18);
#pragma unroll
    for (int i = 0; i < 2; ++i) {
      const int grp = (i << 3) + wid;                 // 0..15
      const int h = (ptile << 2) + (grp >> 2) + dh;   // uniform per instr
      const bool ok = !dummy && ((unsigned)h < 64u);
      const int off = ((pbase + (grp << 4) + srow + (dh << 6) + dw) << 6) + (sch << 4);
      const char* src = ok ? cb + off : zpb + (lane << 4);
      __builtin_amdgcn_global_load_lds((g_void*)src, (l_void*)(dst0 + (grp << 10)), 16, 0, 0);
    }
  };
  auto stageKer = [&](int tn, bool dummy) {
    char* dst0 = L + (tn & 3) * SLOTB + 16384;  // KER at +16KB
    const char* src0 = ktb + ((size_t)tn << 14);
#pragma unroll
    for (int i = 0; i < 2; ++i) {
      const int grp = (i << 3) + wid;
      const char* src = !dummy ? src0 + (grp << 10) + (lane << 4) : zpb + (lane << 4);
      __builtin_amdgcn_global_load_lds((g_void*)src, (l_void*)(dst0 + (grp << 10)), 16, 0, 0);
    }
  };
  // M-side (A) staged in alpha; N-side (B) staged in beta
  auto stageM = [&](int tn, int cibp, int dh, int dw, bool dummy) {
    if (PASS == 1) stageI(tn, cibp, dh, dw, dummy); else stageKer(tn, dummy);
  };
  auto stageN = [&](int tn, int cibp, int dh, int dw, bool dummy) {
    if (PASS == 1) stageKer(tn, dummy); else stageI(tn, cibp, dh, dw, dummy);
  };

  // prologue: N0,M0,N1,M1,N2,M2,N3 (14 loads/wave); drain N0,M0.
  stageN(0, 0, -1, -1, false);
  stageM(0, 0, -1, -1, false);
  stageN(1, 0, -1, 0, false);
  stageM(1, 0, -1, 0, false);
  stageN(2, 0, -1, 1, false);
  stageM(2, 0, -1, 1, false);
  stageN(3, 0, 0, -1, false);
  asm volatile("s_waitcnt vmcnt(10)" ::: "memory");
  __builtin_amdgcn_s_barrier();
  __builtin_amdgcn_sched_barrier(0);

#pragma unroll 1
  for (int c8 = 0; c8 < 8; ++c8) {
#pragma unroll
    for (int s = 0; s < 9; ++s) {  // s compile-time (taps, slots mod pattern)
      const int kk = c8 * 9 + s;
      const int sl = (c8 + s) & 3;  // (c8*9+s)&3
      const char* At = L + sl * SLOTB + ((PASS == 1) ? 0 : 16384);
      const char* Bt = L + sl * SLOTB + ((PASS == 1) ? 16384 : 0);
      const int dw = s % 3 - 1;

      // ---- alpha: 8 ds_read | stage M(kk+3) | 16 MFMA (m0-3) ----
      bf16x8 fal[4], fb[4];
#pragma unroll
      for (int i = 0; i < 4; ++i) fal[i] = *(const bf16x8*)(At + aoff[i]);
#pragma unroll
      for (int j = 0; j < 4; ++j) fb[j] = *(const bf16x8*)(Bt + boff[j]);
      {
        const int s3 = (s + 3) % 9;
        stageM(kk + 3, c8 + (s + 3) / 9, s3 / 3 - 1, s3 % 3 - 1, kk + 3 >= NT);
      }
      __builtin_amdgcn_s_barrier();
      asm volatile("s_waitcnt lgkmcnt(0)" ::: "memory");
      __builtin_amdgcn_sched_barrier(0);
      // w-edge kills (compile-time tap): image side only
      if (PASS == 1) {
        if (dw == -1) fal[0] = killlo ? z8 : fal[0];
        if (dw == 1) fal[3] = killhi ? z8 : fal[3];
      } else {
        if (dw == -1) fb[0] = killlo ? z8 : fb[0];
        if (dw == 1) fb[3] = killhi ? z8 : fb[3];
      }
      __builtin_amdgcn_s_setprio(1);
#pragma unroll
      for (int i = 0; i < 4; ++i)
#pragma unroll
        for (int j = 0; j < 4; ++j)
          acc[i][j] = __builtin_amdgcn_mfma_f32_16x16x32_bf16(fal[i], fb[j], acc[i][j], 0, 0, 0);
      __builtin_amdgcn_s_setprio(0);
      __builtin_amdgcn_s_barrier();
      __builtin_amdgcn_sched_barrier(0);

      // ---- beta: 4 ds_read | stage N(kk+4) | 16 MFMA (m4-7) ----
      bf16x8 fah[4];
#pragma unroll
      for (int i = 0; i < 4; ++i) fah[i] = *(const bf16x8*)(At + aoff[4 + i]);
      {
        const int s4 = (s + 4) % 9;
        stageN(kk + 4, c8 + (s + 4) / 9, s4 / 3 - 1, s4 % 3 - 1, kk + 4 >= NT);
      }
      __builtin_amdgcn_s_barrier();
      asm volatile("s_waitcnt lgkmcnt(0)" ::: "memory");
      __builtin_amdgcn_sched_barrier(0);
      if (PASS == 1) {
        if (dw == -1) fah[0] = killlo ? z8 : fah[0];
        if (dw == 1) fah[3] = killhi ? z8 : fah[3];
      }
      __builtin_amdgcn_s_setprio(1);
#pragma unroll
      for (int i = 0; i < 4; ++i)
#pragma unroll
        for (int j = 0; j < 4; ++j)
          acc[4 + i][j] =
              __builtin_amdgcn_mfma_f32_16x16x32_bf16(fah[i], fb[j], acc[4 + i][j], 0, 0, 0);
      __builtin_amdgcn_s_setprio(0);
      // counted: leaves N(kk+4), M(kk+3), N(kk+3) = 6 loads in flight
      asm volatile("s_waitcnt vmcnt(6)" ::: "memory");
      __builtin_amdgcn_s_barrier();
      __builtin_amdgcn_sched_barrier(0);
    }
  }
  asm volatile("s_waitcnt vmcnt(0)" ::: "memory");  // drain tail dummies
  __builtin_amdgcn_sched_barrier(0);

  const int lg = lane >> 4;
  const int ln = lane & 15;
  if (PASS == 1) {
    __hip_bfloat16* ho = (__hip_bfloat16*)outp;  // ht2 [b][cib][pix][32]
#pragma unroll
    for (int i = 0; i < 8; ++i)
#pragma unroll
      for (int j = 0; j < 4; ++j)
#pragma unroll
        for (int r = 0; r < 4; ++r) {
          int pixel = pbase + (wm << 7) + (i << 4) + (lg << 2) + r;
          int co = (wn << 6) + (j << 4) + ln;
          float v = acc[i][j][r];
          v = v > 0.f ? v : 0.f;
          ho[((size_t)(b * 8 + (co >> 5)) << 17) + ((size_t)pixel << 5) + (co & 31)] =
              __float2bfloat16(v);
        }
  } else {
    float* oo = (float*)outp;
#pragma unroll
    for (int i = 0; i < 8; ++i)
#pragma unroll
      for (int j = 0; j < 4; ++j)
#pragma unroll
        for (int r = 0; r < 4; ++r) {
          int co = (wm << 7) + (i << 4) + (lg << 2) + r;
          int pixel = pbase + (wn << 6) + (j << 4) + ln;
          size_t idx = ((size_t)(b * NC + co) << 12) + pixel;
          float v = acc[i][j][r] + xres[idx];
          oo[idx] = v > 0.f ? v : 0.f;
        }
  }
}

extern "C" void kernel_launch(void* const* d_in, const int* in_sizes, int n_in,
                              void* d_out, int out_size, void* d_ws, size_t ws_size,
                              hipStream_t stream) {
  const float* x = (const float*)d_in[0];
  const float* k1 = (const float*)d_in[1];
  const float* k2 = (const float*)d_in[2];

  // ws: pad 256B | xt2 (33.6MB) | ht2 (33.6MB) | kt2 (18.9MB) | zp (8KB)
  char* w = (char*)d_ws;
  __hip_bfloat16* xt2 = (__hip_bfloat16*)(w + 256);
  __hip_bfloat16* ht2 = xt2 + (size_t)NB * 8 * NHW * 32;
  __hip_bfloat16* kt2 = ht2 + (size_t)NB * 8 * NHW * 32;
  float* zp = (float*)(kt2 + (size_t)NB * NT * 256 * 32);

  prep_xt2<<<dim3(64, 4, NB), 256, 0, stream>>>(x, xt2, zp);
  prep_kt2<<<dim3(NB * NC), 256, 0, stream>>>(k1, kt2);
  conv_gemm<1><<<dim3(256), 512, 0, stream>>>(xt2, kt2, nullptr,
                                              (const __hip_bfloat16*)zp, (void*)ht2);
  prep_kt2<<<dim3(NB * NC), 256, 0, stream>>>(k2, kt2);
  conv_gemm<2><<<dim3(256), 512, 0, stream>>>(ht2, kt2, x,
                                              (const __hip_bfloat16*)zp, d_out);
}

// Round 11
// 183.428 us; speedup vs baseline: 1.4330x; 1.0139x over previous
//
#include <hip/hip_runtime.h>
#include <hip/hip_bf16.h>
#include <stdint.h>

typedef __attribute__((ext_vector_type(8))) short bf16x8;
typedef __attribute__((ext_vector_type(4))) float f32x4;
typedef __attribute__((address_space(1))) const void g_void;
typedef __attribute__((address_space(3))) void l_void;

#define NB 16
#define NC 256
#define NHW 4096
#define NT 72        // K-steps: 9 taps x 8 ci-blocks
#define SLOTB 32768  // per pipeline slot: IMG 16KB + KER 16KB (3 slots = 96KB)

// ---------- prep: x NCHW f32 -> xt2 [b][cib][4096 pix][32 ci] bf16 (+zp init) ----
__global__ __launch_bounds__(256) void prep_xt2(const float* __restrict__ x,
                                                __hip_bfloat16* __restrict__ xt2,
                                                float* __restrict__ zp) {
  __shared__ float tile[64][65];
  const int b = blockIdx.z;
  const int cb = blockIdx.y << 6;
  const int pb = blockIdx.x << 6;
  if (blockIdx.x == 0 && blockIdx.y == 0 && blockIdx.z == 0) {
#pragma unroll
    for (int q = 0; q < 8; ++q) zp[(q << 8) + threadIdx.x] = 0.f;
  }
  const float* xs = x + ((size_t)(b * NC + cb) << 12) + pb;
#pragma unroll
  for (int k = 0; k < 16; ++k) {
    int idx = threadIdx.x + (k << 8);
    int c = idx >> 6, p = idx & 63;
    tile[p][c] = xs[((size_t)c << 12) + p];
  }
  __syncthreads();
#pragma unroll
  for (int k = 0; k < 16; ++k) {
    int idx = threadIdx.x + (k << 8);
    int p = idx >> 6, c = idx & 63;
    int P = pb + p, C = cb + c;
    xt2[((size_t)(b * 8 + (C >> 5)) << 17) + ((size_t)P << 5) + (C & 31)] =
        __float2bfloat16(tile[p][c]);
  }
}

// ---------- prep: kernel [b][co][ci][3][3] f32 -> kt2 [b][tn][256 co][32 k] bf16 ----
// tn = cib*9+s; 16KB contiguous per (b,tn); chunk pre-swizzled:
// stored-slot = chunk ^ ((co>>1)&3)
__global__ __launch_bounds__(256) void prep_kt2(const float* __restrict__ kin,
                                                __hip_bfloat16* __restrict__ kt2) {
  const int bco = blockIdx.x;  // b*256 + co
  const int b = bco >> 8, co = bco & 255;
  const size_t base = (size_t)bco * 2304;
  const int ci = threadIdx.x;
  float v[9];
#pragma unroll
  for (int s = 0; s < 9; ++s) v[s] = kin[base + ci * 9 + s];
  const int cib = ci >> 5, chunk = (ci >> 3) & 3, e = ci & 7;
  const int sc = chunk ^ ((co >> 1) & 3);
#pragma unroll
  for (int s = 0; s < 9; ++s) {
    const size_t dst = (((size_t)(b * NT + cib * 9 + s)) << 13) +
                       (co << 5) + (sc << 3) + e;
    kt2[dst] = __float2bfloat16(v[s]);
  }
}

// ---------- implicit-GEMM conv, 256x256 tile, 1 phase per K-step (32-MFMA) ----
// PASS 1: A=image(M=pixel), B=kernel(N=co), out = ht2 bf16 [b][cib][pix][32] (relu)
// PASS 2: A=kernel(M=co), B=image(N=pixel), out = fp32 NCHW (x + .., relu)
template <int PASS>
__global__ __launch_bounds__(512, 2) void conv_gemm(
    const __hip_bfloat16* __restrict__ img2,  // [B][8][4096][32] (xt2 or ht2)
    const __hip_bfloat16* __restrict__ kt2,   // [B][72][256][32] pre-swizzled
    const float* __restrict__ xres,           // pass2 residual (NCHW f32)
    const __hip_bfloat16* __restrict__ zp,    // 8KB zeros
    void* __restrict__ outp) {
  __shared__ __align__(16) char L[3 * SLOTB];  // slot: [IMG 16KB | KER 16KB]

  const int tid = threadIdx.x;
  const int lane = tid & 63;
  const int wid = tid >> 6;  // 0..7
  const int wm = wid >> 2;   // 0..1  (M half: 128 rows)
  const int wn = wid & 3;    // 0..3  (N quarter: 64 cols)

  // XCD-affine: XCD x owns 32 logical blocks = 2 complete samples
  const int orig = blockIdx.x;
  const int g = ((orig & 7) << 5) + (orig >> 3);
  const int b = g >> 4;
  const int ptile = g & 15;
  const int pbase = ptile << 8;  // 256 pixels

  const char* xb = (const char*)img2 + ((size_t)b << 21);         // 2MB/sample
  const char* ktb = (const char*)kt2 + ((size_t)(b * NT) << 14);  // 16KB/tn
  const char* zpb = (const char*)zp;

  // staging lane geometry: each instr = 16 rows x 64B contiguous; lane -> row
  // +(lane>>2), HW slot lane&3; pre-swizzled source chunk
  const int srow = lane >> 2;
  const int sch = (lane & 3) ^ ((srow >> 1) & 3);

  // fragment read offsets (bytes): A rows = wm*128 + i*16, B rows = wn*64 + j*16
  int aoff[8], boff[4];
#pragma unroll
  for (int i = 0; i < 8; ++i) {
    const int ma = (wm << 7) + (i << 4) + (lane & 15);
    aoff[i] = (ma << 6) + ((((lane >> 4) ^ ((ma >> 1) & 3))) << 4);
  }
#pragma unroll
  for (int j = 0; j < 4; ++j) {
    const int nb = (wn << 6) + (j << 4) + (lane & 15);
    boff[j] = (nb << 6) + ((((lane >> 4) ^ ((nb >> 1) & 3))) << 4);
  }
  const bool killlo = (lane & 15) == 0;
  const bool killhi = (lane & 15) == 15;
  const bf16x8 z8 = {0, 0, 0, 0, 0, 0, 0, 0};

  f32x4 acc[8][4];
#pragma unroll
  for (int i = 0; i < 8; ++i)
#pragma unroll
    for (int j = 0; j < 4; ++j) acc[i][j] = (f32x4){0.f, 0.f, 0.f, 0.f};

  // image tile stage: 16KB contiguous at tap offset; per-instr uniform h-redirect
  auto stageI = [&](int tn, int cibp, int dh, int dw, bool dummy) {
    char* dst0 = L + (tn % 3) * SLOTB;  // IMG at +0
    const char* cb = xb + ((size_t)(cibp & 7) << 18);
#pragma unroll
    for (int i = 0; i < 2; ++i) {
      const int grp = (i << 3) + wid;                // 0..15
      const int h = (ptile << 2) + (grp >> 2) + dh;  // uniform per instr
      const bool ok = !dummy && ((unsigned)h < 64u);
      const int off = ((pbase + (grp << 4) + srow + (dh << 6) + dw) << 6) + (sch << 4);
      const char* src = ok ? cb + off : zpb + (lane << 4);
      __builtin_amdgcn_global_load_lds((g_void*)src, (l_void*)(dst0 + (grp << 10)), 16, 0, 0);
    }
  };
  auto stageKer = [&](int tn, bool dummy) {
    char* dst0 = L + (tn % 3) * SLOTB + 16384;  // KER at +16KB
    const char* src0 = ktb + ((size_t)tn << 14);
#pragma unroll
    for (int i = 0; i < 2; ++i) {
      const int grp = (i << 3) + wid;
      const char* src = !dummy ? src0 + (grp << 10) + (lane << 4) : zpb + (lane << 4);
      __builtin_amdgcn_global_load_lds((g_void*)src, (l_void*)(dst0 + (grp << 10)), 16, 0, 0);
    }
  };
  auto stageBoth = [&](int tn, int cibp, int dh, int dw, bool dummy) {
    stageI(tn, cibp, dh, dw, dummy);
    stageKer(tn, dummy);
  };

  // prologue: tiles 0 (tap -1,-1) and 1 (tap -1,0) staged; drain tile 0.
  stageBoth(0, 0, -1, -1, false);
  stageBoth(1, 0, -1, 0, false);
  asm volatile("s_waitcnt vmcnt(4)" ::: "memory");
  __builtin_amdgcn_s_barrier();
  __builtin_amdgcn_sched_barrier(0);

#pragma unroll 1
  for (int c9 = 0; c9 < 8; ++c9) {
#pragma unroll
    for (int s = 0; s < 9; ++s) {  // s compile-time; slot = s%3 (9 % 3 == 0)
      const int kk = c9 * 9 + s;
      const int sl = s % 3;
      const char* At = L + sl * SLOTB + ((PASS == 1) ? 0 : 16384);
      const char* Bt = L + sl * SLOTB + ((PASS == 1) ? 16384 : 0);
      const int dw = s % 3 - 1;

      // 12 fragment ds_reads (whole K-step) | stage tile kk+2 into slot (s+2)%3
      bf16x8 fa[8], fb[4];
#pragma unroll
      for (int i = 0; i < 8; ++i) fa[i] = *(const bf16x8*)(At + aoff[i]);
#pragma unroll
      for (int j = 0; j < 4; ++j) fb[j] = *(const bf16x8*)(Bt + boff[j]);
      {
        const int s2 = (s + 2) % 9;
        stageBoth(kk + 2, c9 + (s + 2) / 9, s2 / 3 - 1, s2 % 3 - 1, kk + 2 >= NT);
      }
      __builtin_amdgcn_s_barrier();
      asm volatile("s_waitcnt lgkmcnt(0)" ::: "memory");
      __builtin_amdgcn_sched_barrier(0);
      // w-edge wrap kills (compile-time tap): image-side frags only
      if (PASS == 1) {
        if (dw == -1) {
          fa[0] = killlo ? z8 : fa[0];
          fa[4] = killlo ? z8 : fa[4];
        }
        if (dw == 1) {
          fa[3] = killhi ? z8 : fa[3];
          fa[7] = killhi ? z8 : fa[7];
        }
      } else {
        if (dw == -1) fb[0] = killlo ? z8 : fb[0];
        if (dw == 1) fb[3] = killhi ? z8 : fb[3];
      }
      __builtin_amdgcn_s_setprio(1);
#pragma unroll
      for (int i = 0; i < 8; ++i)
#pragma unroll
        for (int j = 0; j < 4; ++j)
          acc[i][j] = __builtin_amdgcn_mfma_f32_16x16x32_bf16(fa[i], fb[j], acc[i][j], 0, 0, 0);
      __builtin_amdgcn_s_setprio(0);
      // counted: keep tile kk+2's 4 loads in flight; drains tile kk+1
      asm volatile("s_waitcnt vmcnt(4)" ::: "memory");
      __builtin_amdgcn_s_barrier();
      __builtin_amdgcn_sched_barrier(0);
    }
  }
  asm volatile("s_waitcnt vmcnt(0)" ::: "memory");  // drain tail dummies
  __builtin_amdgcn_sched_barrier(0);

  const int lg = lane >> 4;
  const int ln = lane & 15;
  if (PASS == 1) {
    __hip_bfloat16* ho = (__hip_bfloat16*)outp;  // ht2 [b][cib][pix][32]
#pragma unroll
    for (int i = 0; i < 8; ++i)
#pragma unroll
      for (int j = 0; j < 4; ++j)
#pragma unroll
        for (int r = 0; r < 4; ++r) {
          int pixel = pbase + (wm << 7) + (i << 4) + (lg << 2) + r;
          int co = (wn << 6) + (j << 4) + ln;
          float v = acc[i][j][r];
          v = v > 0.f ? v : 0.f;
          ho[((size_t)(b * 8 + (co >> 5)) << 17) + ((size_t)pixel << 5) + (co & 31)] =
              __float2bfloat16(v);
        }
  } else {
    float* oo = (float*)outp;
#pragma unroll
    for (int i = 0; i < 8; ++i)
#pragma unroll
      for (int j = 0; j < 4; ++j)
#pragma unroll
        for (int r = 0; r < 4; ++r) {
          int co = (wm << 7) + (i << 4) + (lg << 2) + r;
          int pixel = pbase + (wn << 6) + (j << 4) + ln;
          size_t idx = ((size_t)(b * NC + co) << 12) + pixel;
          float v = acc[i][j][r] + xres[idx];
          oo[idx] = v > 0.f ? v : 0.f;
        }
  }
}

extern "C" void kernel_launch(void* const* d_in, const int* in_sizes, int n_in,
                              void* d_out, int out_size, void* d_ws, size_t ws_size,
                              hipStream_t stream) {
  const float* x = (const float*)d_in[0];
  const float* k1 = (const float*)d_in[1];
  const float* k2 = (const float*)d_in[2];

  // ws: pad 256B | xt2 (33.6MB) | ht2 (33.6MB) | kt2 (18.9MB) | zp (8KB)
  char* w = (char*)d_ws;
  __hip_bfloat16* xt2 = (__hip_bfloat16*)(w + 256);
  __hip_bfloat16* ht2 = xt2 + (size_t)NB * 8 * NHW * 32;
  __hip_bfloat16* kt2 = ht2 + (size_t)NB * 8 * NHW * 32;
  float* zp = (float*)(kt2 + (size_t)NB * NT * 256 * 32);

  prep_xt2<<<dim3(64, 4, NB), 256, 0, stream>>>(x, xt2, zp);
  prep_kt2<<<dim3(NB * NC), 256, 0, stream>>>(k1, kt2);
  conv_gemm<1><<<dim3(256), 512, 0, stream>>>(xt2, kt2, nullptr,
                                              (const __hip_bfloat16*)zp, (void*)ht2);
  prep_kt2<<<dim3(NB * NC), 256, 0, stream>>>(k2, kt2);
  conv_gemm<2><<<dim3(256), 512, 0, stream>>>(ht2, kt2, x,
                                              (const __hip_bfloat16*)zp, d_out);
}

// Round 12
// 175.432 us; speedup vs baseline: 1.4983x; 1.0456x over previous
//
#include <hip/hip_runtime.h>
#include <hip/hip_bf16.h>
#include <stdint.h>

typedef __attribute__((ext_vector_type(8))) short bf16x8;
typedef __attribute__((ext_vector_type(4))) float f32x4;
typedef __attribute__((address_space(1))) const void g_void;
typedef __attribute__((address_space(3))) void l_void;

#define NB 16
#define NC 256
#define NHW 4096
#define NT 72        // K-steps: 9 taps x 8 ci-blocks
#define SLOTB 32768  // per pipeline slot: IMG 16KB + KER 16KB (3 slots = 96KB)

// ---------- prep: x NCHW f32 -> xt2 [b][cib][4096 pix][32 ci] bf16 (+zp init) ----
__global__ __launch_bounds__(256) void prep_xt2(const float* __restrict__ x,
                                                __hip_bfloat16* __restrict__ xt2,
                                                float* __restrict__ zp) {
  __shared__ float tile[64][65];
  const int b = blockIdx.z;
  const int cb = blockIdx.y << 6;
  const int pb = blockIdx.x << 6;
  if (blockIdx.x == 0 && blockIdx.y == 0 && blockIdx.z == 0) {
#pragma unroll
    for (int q = 0; q < 8; ++q) zp[(q << 8) + threadIdx.x] = 0.f;
  }
  const float* xs = x + ((size_t)(b * NC + cb) << 12) + pb;
#pragma unroll
  for (int k = 0; k < 16; ++k) {
    int idx = threadIdx.x + (k << 8);
    int c = idx >> 6, p = idx & 63;
    tile[p][c] = xs[((size_t)c << 12) + p];
  }
  __syncthreads();
#pragma unroll
  for (int k = 0; k < 16; ++k) {
    int idx = threadIdx.x + (k << 8);
    int p = idx >> 6, c = idx & 63;
    int P = pb + p, C = cb + c;
    xt2[((size_t)(b * 8 + (C >> 5)) << 17) + ((size_t)P << 5) + (C & 31)] =
        __float2bfloat16(tile[p][c]);
  }
}

// ---------- prep: kernel [b][co][ci][3][3] f32 -> kt2 [b][tn][256 co][32 k] bf16 ----
// tn = cib*9+s; 16KB contiguous per (b,tn); chunk pre-swizzled:
// stored-slot = chunk ^ ((co>>1)&3)
__global__ __launch_bounds__(256) void prep_kt2(const float* __restrict__ kin,
                                                __hip_bfloat16* __restrict__ kt2) {
  const int bco = blockIdx.x;  // b*256 + co
  const int b = bco >> 8, co = bco & 255;
  const size_t base = (size_t)bco * 2304;
  const int ci = threadIdx.x;
  float v[9];
#pragma unroll
  for (int s = 0; s < 9; ++s) v[s] = kin[base + ci * 9 + s];
  const int cib = ci >> 5, chunk = (ci >> 3) & 3, e = ci & 7;
  const int sc = chunk ^ ((co >> 1) & 3);
#pragma unroll
  for (int s = 0; s < 9; ++s) {
    const size_t dst = (((size_t)(b * NT + cib * 9 + s)) << 13) +
                       (co << 5) + (sc << 3) + e;
    kt2[dst] = __float2bfloat16(v[s]);
  }
}

// ---------- implicit-GEMM conv, 256x256 tile, partial-lgkm sub-cluster pipeline ----
// PASS 1: A=image(M=pixel), B=kernel(N=co), out = ht2 bf16 [b][cib][pix][32] (relu)
// PASS 2: A=kernel(M=co), B=image(N=pixel), out = fp32 NCHW (x + .., relu)
template <int PASS>
__global__ __launch_bounds__(512, 2) void conv_gemm(
    const __hip_bfloat16* __restrict__ img2,  // [B][8][4096][32] (xt2 or ht2)
    const __hip_bfloat16* __restrict__ kt2,   // [B][72][256][32] pre-swizzled
    const float* __restrict__ xres,           // pass2 residual (NCHW f32)
    const __hip_bfloat16* __restrict__ zp,    // 8KB zeros
    void* __restrict__ outp) {
  __shared__ __align__(16) char L[3 * SLOTB];  // slot: [IMG 16KB | KER 16KB]

  const int tid = threadIdx.x;
  const int lane = tid & 63;
  const int wid = tid >> 6;  // 0..7
  const int wm = wid >> 2;   // 0..1  (M half: 128 rows)
  const int wn = wid & 3;    // 0..3  (N quarter: 64 cols)

  // XCD-affine: XCD x owns 32 logical blocks = 2 complete samples
  const int orig = blockIdx.x;
  const int g = ((orig & 7) << 5) + (orig >> 3);
  const int b = g >> 4;
  const int ptile = g & 15;
  const int pbase = ptile << 8;  // 256 pixels

  const char* xb = (const char*)img2 + ((size_t)b << 21);         // 2MB/sample
  const char* ktb = (const char*)kt2 + ((size_t)(b * NT) << 14);  // 16KB/tn
  const char* zpb = (const char*)zp;

  // staging lane geometry: each instr = 16 rows x 64B contiguous; lane -> row
  // +(lane>>2), HW slot lane&3; pre-swizzled source chunk
  const int srow = lane >> 2;
  const int sch = (lane & 3) ^ ((srow >> 1) & 3);

  // fragment read offsets (bytes): A rows = wm*128 + i*16, B rows = wn*64 + j*16
  int aoff[8], boff[4];
#pragma unroll
  for (int i = 0; i < 8; ++i) {
    const int ma = (wm << 7) + (i << 4) + (lane & 15);
    aoff[i] = (ma << 6) + ((((lane >> 4) ^ ((ma >> 1) & 3))) << 4);
  }
#pragma unroll
  for (int j = 0; j < 4; ++j) {
    const int nb = (wn << 6) + (j << 4) + (lane & 15);
    boff[j] = (nb << 6) + ((((lane >> 4) ^ ((nb >> 1) & 3))) << 4);
  }
  const bool killlo = (lane & 15) == 0;
  const bool killhi = (lane & 15) == 15;
  const bf16x8 z8 = {0, 0, 0, 0, 0, 0, 0, 0};

  f32x4 acc[8][4];
#pragma unroll
  for (int i = 0; i < 8; ++i)
#pragma unroll
    for (int j = 0; j < 4; ++j) acc[i][j] = (f32x4){0.f, 0.f, 0.f, 0.f};

  // image tile stage: 16KB contiguous at tap offset; per-instr uniform h-redirect
  auto stageI = [&](int tn, int cibp, int dh, int dw, bool dummy) {
    char* dst0 = L + (tn % 3) * SLOTB;  // IMG at +0
    const char* cb = xb + ((size_t)(cibp & 7) << 18);
#pragma unroll
    for (int i = 0; i < 2; ++i) {
      const int grp = (i << 3) + wid;                // 0..15
      const int h = (ptile << 2) + (grp >> 2) + dh;  // uniform per instr
      const bool ok = !dummy && ((unsigned)h < 64u);
      const int off = ((pbase + (grp << 4) + srow + (dh << 6) + dw) << 6) + (sch << 4);
      const char* src = ok ? cb + off : zpb + (lane << 4);
      __builtin_amdgcn_global_load_lds((g_void*)src, (l_void*)(dst0 + (grp << 10)), 16, 0, 0);
    }
  };
  auto stageKer = [&](int tn, bool dummy) {
    char* dst0 = L + (tn % 3) * SLOTB + 16384;  // KER at +16KB
    const char* src0 = ktb + ((size_t)tn << 14);
#pragma unroll
    for (int i = 0; i < 2; ++i) {
      const int grp = (i << 3) + wid;
      const char* src = !dummy ? src0 + (grp << 10) + (lane << 4) : zpb + (lane << 4);
      __builtin_amdgcn_global_load_lds((g_void*)src, (l_void*)(dst0 + (grp << 10)), 16, 0, 0);
    }
  };
  auto stageBoth = [&](int tn, int cibp, int dh, int dw, bool dummy) {
    stageI(tn, cibp, dh, dw, dummy);
    stageKer(tn, dummy);
  };

  // prologue: tiles 0 (tap -1,-1) and 1 (tap -1,0) staged; loop top drains.
  stageBoth(0, 0, -1, -1, false);
  stageBoth(1, 0, -1, 0, false);

#pragma unroll 1
  for (int c9 = 0; c9 < 8; ++c9) {
#pragma unroll
    for (int s = 0; s < 9; ++s) {  // s compile-time; slot = s%3 (9 % 3 == 0)
      const int kk = c9 * 9 + s;
      const int sl = s % 3;
      const char* At = L + sl * SLOTB + ((PASS == 1) ? 0 : 16384);
      const char* Bt = L + sl * SLOTB + ((PASS == 1) ? 16384 : 0);
      const int dw = s % 3 - 1;

      // single per-phase rendezvous: own tile-kk loads drained, then barrier.
      // (passing it implies every wave's phase kk-1 ds_reads completed, so the
      //  stage below may overwrite slot (s+2)%3 == (s-1)%3 safely)
      asm volatile("s_waitcnt vmcnt(4)" ::: "memory");
      __builtin_amdgcn_s_barrier();
      __builtin_amdgcn_sched_barrier(0);

      // issue all 12 ds_reads in pinned groups (consume order)
      bf16x8 fb[4], fa[8];
      fb[0] = *(const bf16x8*)(Bt + boff[0]);
      fb[1] = *(const bf16x8*)(Bt + boff[1]);
      fb[2] = *(const bf16x8*)(Bt + boff[2]);
      fb[3] = *(const bf16x8*)(Bt + boff[3]);
      fa[0] = *(const bf16x8*)(At + aoff[0]);
      fa[1] = *(const bf16x8*)(At + aoff[1]);
      __builtin_amdgcn_sched_barrier(0);
      fa[2] = *(const bf16x8*)(At + aoff[2]);
      fa[3] = *(const bf16x8*)(At + aoff[3]);
      __builtin_amdgcn_sched_barrier(0);
      fa[4] = *(const bf16x8*)(At + aoff[4]);
      fa[5] = *(const bf16x8*)(At + aoff[5]);
      __builtin_amdgcn_sched_barrier(0);
      fa[6] = *(const bf16x8*)(At + aoff[6]);
      fa[7] = *(const bf16x8*)(At + aoff[7]);
      __builtin_amdgcn_sched_barrier(0);

      // ---- cluster 0: needs fb0-3, fa0-1 (first 6 reads) ----
      asm volatile("s_waitcnt lgkmcnt(6)" ::: "memory");
      __builtin_amdgcn_sched_barrier(0);
      if (PASS == 1) {
        if (dw == -1) fa[0] = killlo ? z8 : fa[0];
      } else {
        if (dw == -1) fb[0] = killlo ? z8 : fb[0];
        if (dw == 1) fb[3] = killhi ? z8 : fb[3];
      }
      __builtin_amdgcn_s_setprio(1);
#pragma unroll
      for (int j = 0; j < 4; ++j)
        acc[0][j] = __builtin_amdgcn_mfma_f32_16x16x32_bf16(fa[0], fb[j], acc[0][j], 0, 0, 0);
#pragma unroll
      for (int j = 0; j < 4; ++j)
        acc[1][j] = __builtin_amdgcn_mfma_f32_16x16x32_bf16(fa[1], fb[j], acc[1][j], 0, 0, 0);
      __builtin_amdgcn_sched_barrier(0);

      // stage tile kk+2 (DMA latency hidden under clusters 1-3)
      {
        const int s2 = (s + 2) % 9;
        stageBoth(kk + 2, c9 + (s + 2) / 9, s2 / 3 - 1, s2 % 3 - 1, kk + 2 >= NT);
      }
      __builtin_amdgcn_sched_barrier(0);

      // ---- cluster 1: + fa2,3 ----
      asm volatile("s_waitcnt lgkmcnt(4)" ::: "memory");
      __builtin_amdgcn_sched_barrier(0);
      if (PASS == 1 && dw == 1) fa[3] = killhi ? z8 : fa[3];
#pragma unroll
      for (int j = 0; j < 4; ++j)
        acc[2][j] = __builtin_amdgcn_mfma_f32_16x16x32_bf16(fa[2], fb[j], acc[2][j], 0, 0, 0);
#pragma unroll
      for (int j = 0; j < 4; ++j)
        acc[3][j] = __builtin_amdgcn_mfma_f32_16x16x32_bf16(fa[3], fb[j], acc[3][j], 0, 0, 0);
      __builtin_amdgcn_sched_barrier(0);

      // ---- cluster 2: + fa4,5 ----
      asm volatile("s_waitcnt lgkmcnt(2)" ::: "memory");
      __builtin_amdgcn_sched_barrier(0);
      if (PASS == 1 && dw == -1) fa[4] = killlo ? z8 : fa[4];
#pragma unroll
      for (int j = 0; j < 4; ++j)
        acc[4][j] = __builtin_amdgcn_mfma_f32_16x16x32_bf16(fa[4], fb[j], acc[4][j], 0, 0, 0);
#pragma unroll
      for (int j = 0; j < 4; ++j)
        acc[5][j] = __builtin_amdgcn_mfma_f32_16x16x32_bf16(fa[5], fb[j], acc[5][j], 0, 0, 0);
      __builtin_amdgcn_sched_barrier(0);

      // ---- cluster 3: + fa6,7 ----
      asm volatile("s_waitcnt lgkmcnt(0)" ::: "memory");
      __builtin_amdgcn_sched_barrier(0);
      if (PASS == 1 && dw == 1) fa[7] = killhi ? z8 : fa[7];
#pragma unroll
      for (int j = 0; j < 4; ++j)
        acc[6][j] = __builtin_amdgcn_mfma_f32_16x16x32_bf16(fa[6], fb[j], acc[6][j], 0, 0, 0);
#pragma unroll
      for (int j = 0; j < 4; ++j)
        acc[7][j] = __builtin_amdgcn_mfma_f32_16x16x32_bf16(fa[7], fb[j], acc[7][j], 0, 0, 0);
      __builtin_amdgcn_s_setprio(0);
      __builtin_amdgcn_sched_barrier(0);
    }
  }
  asm volatile("s_waitcnt vmcnt(0)" ::: "memory");  // drain tail dummies
  __builtin_amdgcn_sched_barrier(0);

  const int lg = lane >> 4;
  const int ln = lane & 15;
  if (PASS == 1) {
    __hip_bfloat16* ho = (__hip_bfloat16*)outp;  // ht2 [b][cib][pix][32]
#pragma unroll
    for (int i = 0; i < 8; ++i)
#pragma unroll
      for (int j = 0; j < 4; ++j)
#pragma unroll
        for (int r = 0; r < 4; ++r) {
          int pixel = pbase + (wm << 7) + (i << 4) + (lg << 2) + r;
          int co = (wn << 6) + (j << 4) + ln;
          float v = acc[i][j][r];
          v = v > 0.f ? v : 0.f;
          ho[((size_t)(b * 8 + (co >> 5)) << 17) + ((size_t)pixel << 5) + (co & 31)] =
              __float2bfloat16(v);
        }
  } else {
    float* oo = (float*)outp;
#pragma unroll
    for (int i = 0; i < 8; ++i)
#pragma unroll
      for (int j = 0; j < 4; ++j)
#pragma unroll
        for (int r = 0; r < 4; ++r) {
          int co = (wm << 7) + (i << 4) + (lg << 2) + r;
          int pixel = pbase + (wn << 6) + (j << 4) + ln;
          size_t idx = ((size_t)(b * NC + co) << 12) + pixel;
          float v = acc[i][j][r] + xres[idx];
          oo[idx] = v > 0.f ? v : 0.f;
        }
  }
}

extern "C" void kernel_launch(void* const* d_in, const int* in_sizes, int n_in,
                              void* d_out, int out_size, void* d_ws, size_t ws_size,
                              hipStream_t stream) {
  const float* x = (const float*)d_in[0];
  const float* k1 = (const float*)d_in[1];
  const float* k2 = (const float*)d_in[2];

  // ws: pad 256B | xt2 (33.6MB) | ht2 (33.6MB) | kt2 (18.9MB) | zp (8KB)
  char* w = (char*)d_ws;
  __hip_bfloat16* xt2 = (__hip_bfloat16*)(w + 256);
  __hip_bfloat16* ht2 = xt2 + (size_t)NB * 8 * NHW * 32;
  __hip_bfloat16* kt2 = ht2 + (size_t)NB * 8 * NHW * 32;
  float* zp = (float*)(kt2 + (size_t)NB * NT * 256 * 32);

  prep_xt2<<<dim3(64, 4, NB), 256, 0, stream>>>(x, xt2, zp);
  prep_kt2<<<dim3(NB * NC), 256, 0, stream>>>(k1, kt2);
  conv_gemm<1><<<dim3(256), 512, 0, stream>>>(xt2, kt2, nullptr,
                                              (const __hip_bfloat16*)zp, (void*)ht2);
  prep_kt2<<<dim3(NB * NC), 256, 0, stream>>>(k2, kt2);
  conv_gemm<2><<<dim3(256), 512, 0, stream>>>(ht2, kt2, x,
                                              (const __hip_bfloat16*)zp, d_out);
}